// Round 18
// baseline (37439.212 us; speedup 1.0000x reference)
//
#include <hip/hip_runtime.h>
#include <hip/hip_fp16.h>
#include <cstdint>
#include <cstddef>

#define NB 64
#define NT 600
#define NU 80
#define NV 60
#define CS 400
#define NK 10
#define NM 20
#define G4 1600      // 4*CS
#define K1 463
#define K1PAD 470    // 10 slices x 47 (rows 463..469 zero)
#define KF 870       // fused scan2 K: 463 ih + 400 hh + 7 zero-pad (10 slices x 87)
#define NP 121
#define CAT 800
#define FLGS 64

#define OFF_END  0u
#define OFF_W    38400u
#define OFF_MU1  806400u
#define OFF_MU2  1574400u
#define OFF_LS1  2342400u
#define OFF_LS2  3110400u
#define OFF_RHO  3878400u
#define OFF_WOLD 4646400u
#define OFF_KAP  4650240u
#define OFF_H1   4650880u
#define OFF_C1   4676480u
#define OFF_H2   4702080u
#define OFF_C2   4727680u
#define OFF_PHI  4753280u

typedef unsigned short ush;

__device__ __forceinline__ float sigm(float v) { return 1.f / (1.f + expf(-v)); }
__device__ __forceinline__ float hlo(unsigned u) { return __half2float(__ushort_as_half((ush)(u & 0xffffu))); }
__device__ __forceinline__ float hhi(unsigned u) { return __half2float(__ushort_as_half((ush)(u >> 16))); }
__device__ __forceinline__ float h2f(ush v) { return __half2float(__ushort_as_half(v)); }
__device__ __forceinline__ ush f2h(float f) { return __half_as_ushort(__float2half_rn(f)); }

#define FMIX_LO(acc, w32, a) asm("v_fma_mix_f32 %0, %1, %2, %0 op_sel_hi:[1,0,0]" : "+v"(acc) : "v"(w32), "v"(a))
#define FMIX_HI(acc, w32, a) asm("v_fma_mix_f32 %0, %1, %2, %0 op_sel:[1,0,0] op_sel_hi:[1,0,0]" : "+v"(acc) : "v"(w32), "v"(a))

// ---------------------------------------------------------------- prep
// W1P[k][jn] f16, jn = r*400 + g*100 + cl  <->  orig j = g*400 + r*100 + cl; rows 463..469 zero
// W2P[k][jn] f16 PERMUTED: k<463 ih, 463..862 hh, 863..869 zero
__global__ void prep_k(const float* __restrict__ W1ih, const float* __restrict__ W1hh,
                       const float* __restrict__ W2ih, const float* __restrict__ W2hh,
                       const float* __restrict__ Wo,
                       ush* __restrict__ W1P, ush* __restrict__ W2P,
                       ush* __restrict__ WoB) {
    int i = blockIdx.x * blockDim.x + threadIdx.x;
    if (i < K1PAD * G4) {
        int k = i / G4, jn = i % G4;
        int r = jn / 400, q = jn % 400, g = q / 100, cl = q % 100;
        int j = g * 400 + r * 100 + cl;
        float v = (k < 63) ? W1ih[j * 63 + k] : (k < K1) ? W1hh[j * CS + (k - 63)] : 0.f;
        W1P[i] = f2h(v);
    }
    if (i < KF * G4) {
        int k = i / G4, jn = i % G4;
        int r = jn / 400, q = jn % 400, g = q / 100, cl = q % 100;
        int j = g * 400 + r * 100 + cl;
        float v = (k < K1) ? W2ih[j * K1 + k] : (k < 863) ? W2hh[j * CS + (k - K1)] : 0.f;
        W2P[i] = f2h(v);
    }
    if (i < NP * CAT) WoB[i] = f2h(Wo[i]);
}

// ---------------------------------------------------------------- fused scan (LSTM1+attn+LSTM2+head), 4 blocks/batch
__global__ __launch_bounds__(512, 2) void fused_k(
    const float* __restrict__ x, const float* __restrict__ onehots,
    const float* __restrict__ text_lens, const float* __restrict__ w0,
    const float* __restrict__ kap0, const float* __restrict__ h10,
    const float* __restrict__ c10, const float* __restrict__ h20,
    const float* __restrict__ c20, const float* __restrict__ b1,
    const float* __restrict__ b2, const float* __restrict__ Ww,
    const float* __restrict__ bw, const float* __restrict__ bo,
    const ush* __restrict__ W1P, const ush* __restrict__ W2P,
    const ush* __restrict__ WoB, float* __restrict__ outp,
    float* __restrict__ hx1, float* __restrict__ hx2,
    float* __restrict__ hxp, unsigned* __restrict__ flg) {
    const int b = blockIdx.x & 63, r = blockIdx.x >> 6;   // same-XCD per batch
    const int tid = threadIdx.x;
    __shared__ float vin[KF];          // [0:3]=x_t [3:63]=w [63:463]=h1 [463:863]=h2 [863:870]=0
    __shared__ float h1sav[CS];        // h1_{t-1} for head
    __shared__ float cst[100], c2l[100];
    __shared__ float part[4000];       // [ks*400 + rr*50 + jt]
    __shared__ float biasl[400], bias2l[400];
    __shared__ float wwr[30 * 100];
    __shared__ float al[NK], be[NK], kap[NK], phi[NU + 1], bwl[30];
    __shared__ float ps[32];
    __shared__ ush chars[NU];
    __shared__ float tl;
    __shared__ unsigned woS[31 * 403];
    // LDS ~88 KB -> 1 block/CU, grid 256 = all resident

    const int ks = tid / 50, jt = tid % 50;          // tid<500
    const int k0a = ks * 47, k0b = ks * 87;
    const ush* wpa = W1P + (size_t)k0a * G4 + r * 400 + jt * 8;
    const ush* wpb = W2P + (size_t)k0b * G4 + r * 400 + jt * 8;
    const int jlo = r * 30, jcnt = (r == 3) ? 31 : 30;

    // ---- init
    for (int i = tid; i < 3000; i += 512) {
        int g = i / 100, k = i - g * 100;
        wwr[i] = Ww[g * 400 + r * 100 + k];
    }
    {
        const unsigned* WoB4 = (const unsigned*)WoB;
        for (int i = tid; i < jcnt * 400; i += 512) {
            int row = i / 400, col = i % 400;
            woS[row * 403 + col] = WoB4[(jlo + row) * 400 + col];
        }
    }
    if (tid < NU) {
        const float* ohr = onehots + (size_t)b * NU * NV + tid * NV;
        int c = 0;
        for (int v = 0; v < NV; ++v) if (ohr[v] > 0.5f) c = v;
        chars[tid] = (ush)c;
    }
    if (tid < 400) {
        int g = tid / 100, cl = tid % 100;
        biasl[tid]  = b1[g * 400 + r * 100 + cl];
        bias2l[tid] = b2[g * 400 + r * 100 + cl];
        vin[63 + tid]  = h10[b * CS + tid];
        vin[463 + tid] = h20[b * CS + tid];
    }
    if (tid >= 400 && tid < 500) {
        cst[tid - 400] = c10[b * CS + r * 100 + (tid - 400)];
        c2l[tid - 400] = c20[b * CS + r * 100 + (tid - 400)];
    }
    if (tid < 60) vin[3 + tid] = w0[b * NV + tid];
    if (tid >= 60 && tid < 70) kap[tid - 60] = kap0[b * NK + (tid - 60)];
    if (tid >= 70 && tid < 73) vin[tid - 70] = x[(b * NT + 0) * 3 + (tid - 70)];
    if (tid >= 73 && tid < 103) bwl[tid - 73] = bw[tid - 73];
    if (tid == 103) tl = text_lens[b];
    if (tid >= 104 && tid < 111) vin[863 + (tid - 104)] = 0.f;
    __syncthreads();

    for (int t = 0; t < NT; ++t) {
        // P1: scan1 gate partials (stream W1P) || save h1_{t-1}
        if (tid < 500) {
            float a0 = 0.f, a1 = 0.f, a2 = 0.f, a3 = 0.f, a4 = 0.f, a5 = 0.f, a6 = 0.f, a7 = 0.f;
            const ush* wp = wpa;
            #pragma unroll 4
            for (int kk = 0; kk < 47; ++kk, wp += G4) {
                float a_ = vin[k0a + kk];
                uint4 wv = *(const uint4*)wp;
                FMIX_LO(a0, wv.x, a_); FMIX_HI(a1, wv.x, a_);
                FMIX_LO(a2, wv.y, a_); FMIX_HI(a3, wv.y, a_);
                FMIX_LO(a4, wv.z, a_); FMIX_HI(a5, wv.z, a_);
                FMIX_LO(a6, wv.w, a_); FMIX_HI(a7, wv.w, a_);
            }
            float* pp = part + ks * 400 + jt;
            pp[0] = a0; pp[50] = a1; pp[100] = a2; pp[150] = a3;
            pp[200] = a4; pp[250] = a5; pp[300] = a6; pp[350] = a7;
        } else {
            for (int i = tid - 500; i < 400; i += 12) h1sav[i] = vin[63 + i];
        }
        __syncthreads();
        // P2: merged reduce + h1 cell (own 100) + publish
        if (tid < 100) {
            int j0 = tid, j1 = 100 + tid, j2 = 200 + tid, j3 = 300 + tid;
            int o0 = (j0 & 7) * 50 + (j0 >> 3), o1 = (j1 & 7) * 50 + (j1 >> 3);
            int o2 = (j2 & 7) * 50 + (j2 >> 3), o3 = (j3 & 7) * 50 + (j3 >> 3);
            float gi = biasl[j0], gf = biasl[j1], gg = biasl[j2], go = biasl[j3];
            #pragma unroll
            for (int q = 0; q < 10; ++q) {
                const float* pb = part + q * 400;
                gi += pb[o0]; gf += pb[o1]; gg += pb[o2]; go += pb[o3];
            }
            float c = sigm(gf) * cst[tid] + sigm(gi) * tanhf(gg);
            float h = sigm(go) * tanhf(c);
            cst[tid] = c;
            int ci = r * 100 + tid;
            vin[63 + ci] = h;
            __hip_atomic_store(&hx1[(size_t)(t & 1) * (NB * CS) + b * CS + ci], h,
                               __ATOMIC_RELAXED, __HIP_MEMORY_SCOPE_AGENT);
        }
        __syncthreads();
        // P3: attention partials over own h1 slice
        if (tid < 240) {
            int g = tid >> 3, l = tid & 7;
            const float* hl_ = vin + 63 + r * 100;
            const float* wr = wwr + g * 100;
            float s = 0.f;
            #pragma unroll
            for (int m = 0; m < 13; ++m) {
                int k = l + 8 * m;
                if (k < 100) s = fmaf(hl_[k], wr[k], s);
            }
            s += __shfl_down(s, 4, 8);
            s += __shfl_down(s, 2, 8);
            s += __shfl_down(s, 1, 8);
            if (l == 0)
                __hip_atomic_store(&hxp[(size_t)(t & 1) * (NB * 128) + b * 128 + r * 32 + g], s,
                                   __ATOMIC_RELAXED, __HIP_MEMORY_SCOPE_AGENT);
        }
        asm volatile("s_waitcnt vmcnt(0)" ::: "memory");
        __syncthreads();
        // P4: global 4-block barrier
        if (tid == 0) {
            __hip_atomic_fetch_add(&flg[b * FLGS], 1u, __ATOMIC_RELAXED, __HIP_MEMORY_SCOPE_AGENT);
            unsigned tgt = 4u * (unsigned)(t + 1);
            while (__hip_atomic_load(&flg[b * FLGS], __ATOMIC_RELAXED, __HIP_MEMORY_SCOPE_AGENT) < tgt)
                __builtin_amdgcn_s_sleep(1);
        }
        __syncthreads();
        // P5: pull h1_t peers, h2_{t-1} peers, combine attention
        if (tid < 400 && (tid / 100) != r) {
            vin[63 + tid] = __hip_atomic_load(&hx1[(size_t)(t & 1) * (NB * CS) + b * CS + tid],
                                              __ATOMIC_RELAXED, __HIP_MEMORY_SCOPE_AGENT);
        }
        if (tid < 300 && t > 0) {
            int c = tid + ((tid / 100 >= r) ? 100 : 0);
            vin[463 + c] = __hip_atomic_load(&hx2[(size_t)((t - 1) & 1) * (NB * CS) + b * CS + c],
                                             __ATOMIC_RELAXED, __HIP_MEMORY_SCOPE_AGENT);
        }
        if (tid >= 448 && tid < 478) {
            int g = tid - 448;
            const float* pb = hxp + (size_t)(t & 1) * (NB * 128) + b * 128;
            float s = __hip_atomic_load(&pb[g], __ATOMIC_RELAXED, __HIP_MEMORY_SCOPE_AGENT)
                    + __hip_atomic_load(&pb[32 + g], __ATOMIC_RELAXED, __HIP_MEMORY_SCOPE_AGENT)
                    + __hip_atomic_load(&pb[64 + g], __ATOMIC_RELAXED, __HIP_MEMORY_SCOPE_AGENT)
                    + __hip_atomic_load(&pb[96 + g], __ATOMIC_RELAXED, __HIP_MEMORY_SCOPE_AGENT);
            float pv = expf(s + bwl[g]);
            if (g < NK) al[g] = pv;
            else if (g < 2 * NK) be[g - NK] = pv;
            else kap[g - 2 * NK] += pv;
        }
        __syncthreads();
        // P6: head(t-1) [h1sav, h2_{t-1}] || phi(t)
        if (tid < 248) {
            if (t > 0) {
                int jj = tid >> 3, l = tid & 7;
                if (jj < jcnt) {
                    const ush* wrow = (const ush*)(woS + jj * 403) + l * 100;
                    const float* crow = (l < 4) ? (h1sav + l * 100) : (vin + 463 + (l - 4) * 100);
                    float s = 0.f;
                    #pragma unroll
                    for (int i2 = 0; i2 < 50; ++i2) {
                        unsigned wv = *(const unsigned*)(wrow + 2 * i2);
                        float clo = crow[2 * i2], chi = crow[2 * i2 + 1];
                        FMIX_LO(s, wv, clo);
                        FMIX_HI(s, wv, chi);
                    }
                    s += __shfl_down(s, 4, 8);
                    s += __shfl_down(s, 2, 8);
                    s += __shfl_down(s, 1, 8);
                    if (l == 0) ps[jj] = s + bo[jlo + jj];
                }
            }
        } else if (tid >= 320 && tid <= 320 + NU) {
            int u = tid - 320;
            float uu = (float)u, s = 0.f;
            #pragma unroll
            for (int k = 0; k < NK; ++k) { float d = kap[k] - uu; s += al[k] * expf(-be[k] * d * d); }
            phi[u] = s * (80.f / tl);
        }
        __syncthreads();
        // P7: w_t gather || MDN out(t-1)
        if (tid < NV) {
            float s = 0.f;
            #pragma unroll 8
            for (int u = 0; u < NU; ++u)
                if (chars[u] == (ush)tid) s += phi[u];
            vin[3 + tid] = s;
        } else if (t > 0 && tid >= 480 && tid < 480 + 31) {
            int jj = tid - 480;
            if (jj < jcnt) {
                int j = jlo + jj;
                float v = ps[jj];
                const size_t nt_ = (size_t)b * NT + (t - 1);
                if (j == 120) {
                    outp[OFF_END + nt_] = sigm(v);
                } else if (j < 20) {
                    float mx = -1e30f;
                    #pragma unroll
                    for (int m = 0; m < NM; ++m) mx = fmaxf(mx, ps[m]);
                    float sm = 0.f;
                    #pragma unroll
                    for (int m = 0; m < NM; ++m) sm += expf(ps[m] - mx);
                    outp[OFF_W + nt_ * NM + j] = expf(v - mx) / sm;
                } else {
                    int sec = j / 20, idx = j - sec * 20;
                    float o = (sec == 5) ? tanhf(v) : v;
                    unsigned offs = (sec == 1) ? OFF_MU1 : (sec == 2) ? OFF_MU2 :
                                    (sec == 3) ? OFF_LS1 : (sec == 4) ? OFF_LS2 : OFF_RHO;
                    outp[offs + nt_ * NM + idx] = o;
                }
            }
        }
        __syncthreads();
        // P8: scan2 fused gates (stream W2P over [x,w,h1,h2])
        if (tid < 500) {
            float a0 = 0.f, a1 = 0.f, a2 = 0.f, a3 = 0.f, a4 = 0.f, a5 = 0.f, a6 = 0.f, a7 = 0.f;
            const ush* wp = wpb;
            #pragma unroll 4
            for (int kk = 0; kk < 87; ++kk, wp += G4) {
                float a_ = vin[k0b + kk];
                uint4 wv = *(const uint4*)wp;
                FMIX_LO(a0, wv.x, a_); FMIX_HI(a1, wv.x, a_);
                FMIX_LO(a2, wv.y, a_); FMIX_HI(a3, wv.y, a_);
                FMIX_LO(a4, wv.z, a_); FMIX_HI(a5, wv.z, a_);
                FMIX_LO(a6, wv.w, a_); FMIX_HI(a7, wv.w, a_);
            }
            float* pp = part + ks * 400 + jt;
            pp[0] = a0; pp[50] = a1; pp[100] = a2; pp[150] = a3;
            pp[200] = a4; pp[250] = a5; pp[300] = a6; pp[350] = a7;
        }
        __syncthreads();
        // P9: h2 cell (own 100) + publish || x prefetch
        if (tid < 100) {
            int j0 = tid, j1 = 100 + tid, j2 = 200 + tid, j3 = 300 + tid;
            int o0 = (j0 & 7) * 50 + (j0 >> 3), o1 = (j1 & 7) * 50 + (j1 >> 3);
            int o2 = (j2 & 7) * 50 + (j2 >> 3), o3 = (j3 & 7) * 50 + (j3 >> 3);
            float gi = bias2l[j0], gf = bias2l[j1], gg = bias2l[j2], go = bias2l[j3];
            #pragma unroll
            for (int q = 0; q < 10; ++q) {
                const float* pb = part + q * 400;
                gi += pb[o0]; gf += pb[o1]; gg += pb[o2]; go += pb[o3];
            }
            float c = sigm(gf) * c2l[tid] + sigm(gi) * tanhf(gg);
            float h = sigm(go) * tanhf(c);
            c2l[tid] = c;
            int ci = r * 100 + tid;
            vin[463 + ci] = h;
            __hip_atomic_store(&hx2[(size_t)(t & 1) * (NB * CS) + b * CS + ci], h,
                               __ATOMIC_RELAXED, __HIP_MEMORY_SCOPE_AGENT);
        } else if (tid >= 100 && tid < 103) {
            if (t + 1 < NT) vin[tid - 100] = x[(b * NT + t + 1) * 3 + (tid - 100)];
        }
        __syncthreads();
    }

    // ---- flush: barrier round for h2_599, head(599), outputs
    asm volatile("s_waitcnt vmcnt(0)" ::: "memory");
    __syncthreads();
    if (tid == 0) {
        __hip_atomic_fetch_add(&flg[b * FLGS], 1u, __ATOMIC_RELAXED, __HIP_MEMORY_SCOPE_AGENT);
        unsigned tgt = 4u * (unsigned)(NT + 1);
        while (__hip_atomic_load(&flg[b * FLGS], __ATOMIC_RELAXED, __HIP_MEMORY_SCOPE_AGENT) < tgt)
            __builtin_amdgcn_s_sleep(1);
    }
    __syncthreads();
    if (tid < 300) {
        int c = tid + ((tid / 100 >= r) ? 100 : 0);
        vin[463 + c] = __hip_atomic_load(&hx2[(size_t)((NT - 1) & 1) * (NB * CS) + b * CS + c],
                                         __ATOMIC_RELAXED, __HIP_MEMORY_SCOPE_AGENT);
    }
    __syncthreads();
    if (tid < 248) {     // head(599): h1_599 is in vin[63..463), h2_599 in vin[463..863)
        int jj = tid >> 3, l = tid & 7;
        if (jj < jcnt) {
            const ush* wrow = (const ush*)(woS + jj * 403) + l * 100;
            const float* crow = (l < 4) ? (vin + 63 + l * 100) : (vin + 463 + (l - 4) * 100);
            float s = 0.f;
            #pragma unroll
            for (int i2 = 0; i2 < 50; ++i2) {
                unsigned wv = *(const unsigned*)(wrow + 2 * i2);
                float clo = crow[2 * i2], chi = crow[2 * i2 + 1];
                FMIX_LO(s, wv, clo);
                FMIX_HI(s, wv, chi);
            }
            s += __shfl_down(s, 4, 8);
            s += __shfl_down(s, 2, 8);
            s += __shfl_down(s, 1, 8);
            if (l == 0) ps[jj] = s + bo[jlo + jj];
        }
    }
    __syncthreads();
    if (tid < jcnt) {
        int j = jlo + tid;
        float v = ps[tid];
        const size_t nt_ = (size_t)b * NT + (NT - 1);
        if (j == 120) {
            outp[OFF_END + nt_] = sigm(v);
        } else if (j < 20) {
            float mx = -1e30f;
            #pragma unroll
            for (int m = 0; m < NM; ++m) mx = fmaxf(mx, ps[m]);
            float sm = 0.f;
            #pragma unroll
            for (int m = 0; m < NM; ++m) sm += expf(ps[m] - mx);
            outp[OFF_W + nt_ * NM + j] = expf(v - mx) / sm;
        } else {
            int sec = j / 20, idx = j - sec * 20;
            float o = (sec == 5) ? tanhf(v) : v;
            unsigned offs = (sec == 1) ? OFF_MU1 : (sec == 2) ? OFF_MU2 :
                            (sec == 3) ? OFF_LS1 : (sec == 4) ? OFF_LS2 : OFF_RHO;
            outp[offs + nt_ * NM + idx] = o;
        }
    }
    // final states
    if (tid < 100) {
        outp[OFF_C1 + b * CS + r * 100 + tid] = cst[tid];
        outp[OFF_C2 + b * CS + r * 100 + tid] = c2l[tid];
        int ci = r * 100 + tid;
        outp[OFF_H2 + b * CS + ci] = vin[463 + ci];
    }
    if (r == 0) {
        if (tid < 400) outp[OFF_H1 + b * CS + tid] = vin[63 + tid];
        if (tid >= 400 && tid < 460) outp[OFF_WOLD + b * NV + (tid - 400)] = vin[3 + tid - 400];
        if (tid >= 460 && tid < 470) outp[OFF_KAP + b * NK + (tid - 460)] = kap[tid - 460];
        if (tid >= 128 && tid <= 128 + NU) outp[OFF_PHI + b * (NU + 1) + (tid - 128)] = phi[tid - 128];
    }
}

// ---------------------------------------------------------------- launch
extern "C" void kernel_launch(void* const* d_in, const int* in_sizes, int n_in,
                              void* d_out, int out_size, void* d_ws, size_t ws_size,
                              hipStream_t stream) {
    const float* x    = (const float*)d_in[0];
    const float* oh   = (const float*)d_in[1];
    const float* tl   = (const float*)d_in[2];
    const float* w0   = (const float*)d_in[3];
    const float* kp0  = (const float*)d_in[4];
    const float* h10  = (const float*)d_in[5];
    const float* c10  = (const float*)d_in[6];
    const float* h20  = (const float*)d_in[7];
    const float* c20  = (const float*)d_in[8];
    const float* W1ih = (const float*)d_in[9];
    const float* W1hh = (const float*)d_in[10];
    const float* b1   = (const float*)d_in[11];
    const float* Ww   = (const float*)d_in[12];
    const float* bw   = (const float*)d_in[13];
    const float* W2ih = (const float*)d_in[14];
    const float* W2hh = (const float*)d_in[15];
    const float* b2   = (const float*)d_in[16];
    const float* Wo   = (const float*)d_in[17];
    const float* bo   = (const float*)d_in[18];
    float* outp = (float*)d_out;

    char* p = (char*)d_ws;
    auto alloc = [&](size_t bytes) { char* r = p; p += (bytes + 255) & ~(size_t)255; return r; };
    ush*   W1P  = (ush*)  alloc((size_t)K1PAD * G4 * 2);
    ush*   W2P  = (ush*)  alloc((size_t)KF * G4 * 2);
    ush*   WoB  = (ush*)  alloc((size_t)NP * CAT * 2);
    float* hx1  = (float*)alloc((size_t)2 * NB * CS * 4);
    float* hx2  = (float*)alloc((size_t)2 * NB * CS * 4);
    float* hxp  = (float*)alloc((size_t)2 * NB * 128 * 4);
    unsigned* flg = (unsigned*)alloc((size_t)NB * FLGS * 4);

    hipMemsetAsync(flg, 0, (size_t)NB * FLGS * 4, stream);
    prep_k<<<(KF * G4 + 255) / 256, 256, 0, stream>>>(W1ih, W1hh, W2ih, W2hh, Wo,
                                                      W1P, W2P, WoB);
    fused_k<<<4 * NB, 512, 0, stream>>>(x, oh, tl, w0, kp0, h10, c10, h20, c20,
                                        b1, b2, Ww, bw, bo, W1P, W2P, WoB,
                                        outp, hx1, hx2, hxp, flg);
}

// Round 19
// 15376.164 us; speedup vs baseline: 2.4349x; 2.4349x over previous
//
#include <hip/hip_runtime.h>
#include <hip/hip_fp16.h>
#include <cstdint>
#include <cstddef>

#define NB 64
#define NT 600
#define NU 80
#define NV 60
#define CS 400
#define NK 10
#define NM 20
#define G4 1600      // 4*CS
#define K1 463
#define K1PAD 470    // 10 slices x 47 (rows 463..469 zero)
#define K2 463
#define NP 121
#define CAT 800
#define APK 480      // A-panel row stride (f16): [x(3), w(60), h1(400), pad(17)=0]
#define FLGS 64
#define TC 100       // pipeline chunk (steps per fused launch)

#define OFF_END  0u
#define OFF_W    38400u
#define OFF_MU1  806400u
#define OFF_MU2  1574400u
#define OFF_LS1  2342400u
#define OFF_LS2  3110400u
#define OFF_RHO  3878400u
#define OFF_WOLD 4646400u
#define OFF_KAP  4650240u
#define OFF_H1   4650880u
#define OFF_C1   4676480u
#define OFF_H2   4702080u
#define OFF_C2   4727680u
#define OFF_PHI  4753280u

typedef unsigned short ush;

__device__ __forceinline__ float sigm(float v) { return 1.f / (1.f + expf(-v)); }
__device__ __forceinline__ float hlo(unsigned u) { return __half2float(__ushort_as_half((ush)(u & 0xffffu))); }
__device__ __forceinline__ float hhi(unsigned u) { return __half2float(__ushort_as_half((ush)(u >> 16))); }
__device__ __forceinline__ float h2f(ush v) { return __half2float(__ushort_as_half(v)); }
__device__ __forceinline__ ush f2h(float f) { return __half_as_ushort(__float2half_rn(f)); }

#define FMIX_LO(acc, w32, a) asm("v_fma_mix_f32 %0, %1, %2, %0 op_sel_hi:[1,0,0]" : "+v"(acc) : "v"(w32), "v"(a))
#define FMIX_HI(acc, w32, a) asm("v_fma_mix_f32 %0, %1, %2, %0 op_sel:[1,0,0] op_sel_hi:[1,0,0]" : "+v"(acc) : "v"(w32), "v"(a))

// ---------------------------------------------------------------- prep (same as r17)
__global__ void prep_k(const float* __restrict__ W1ih, const float* __restrict__ W1hh,
                       const float* __restrict__ W2ih, const float* __restrict__ W2hh,
                       const float* __restrict__ Wo,
                       ush* __restrict__ W1P, ush* __restrict__ W2T,
                       ush* __restrict__ WoB) {
    int i = blockIdx.x * blockDim.x + threadIdx.x;
    if (i < K1PAD * G4) {
        int k = i / G4, jn = i % G4;
        int r = jn / 400, q = jn % 400, g = q / 100, cl = q % 100;
        int j = g * 400 + r * 100 + cl;
        float v = (k < 63) ? W1ih[j * 63 + k] : (k < K1) ? W1hh[j * CS + (k - 63)] : 0.f;
        W1P[i] = f2h(v);
    }
    if (i < 863 * G4) {
        int k = i / G4, jj = i % G4;
        float v;
        if (k < K2) {
            v = W2ih[jj * K2 + k];
        } else {
            int r = jj / 400, q = jj % 400, g = q / 100, cl = q % 100;
            int j = g * 400 + r * 100 + cl;
            v = W2hh[j * CS + (k - K2)];
        }
        W2T[i] = f2h(v);
    }
    if (i < NP * CAT) WoB[i] = f2h(Wo[i]);
}

// ---------------------------------------------------------------- fused pipelined scan: scan1 chunk c + scan2 chunk c-1
__global__ __launch_bounds__(512, 2) void fused_k(
    const float* __restrict__ x, const float* __restrict__ onehots,
    const float* __restrict__ text_lens, const float* __restrict__ w0,
    const float* __restrict__ kap0, const float* __restrict__ h10,
    const float* __restrict__ c10, const float* __restrict__ h20,
    const float* __restrict__ c20, const float* __restrict__ b1,
    const float* __restrict__ b2, const float* __restrict__ Ww,
    const float* __restrict__ bw, const float* __restrict__ bo,
    const ush* __restrict__ W1P, const ush* __restrict__ W2T,
    const ush* __restrict__ WoB, const ush* __restrict__ Zb,
    ush* __restrict__ Apan, float* __restrict__ outp,
    float* __restrict__ hx1, float* __restrict__ hx2,
    float* __restrict__ hxp, unsigned* __restrict__ flg,
    float* __restrict__ st_c1, float* __restrict__ st_c2,
    float* __restrict__ st_w, float* __restrict__ st_kap,
    int t0A, int t0S, int doA, int doS, int lastA, int lastS) {
    const int b = blockIdx.x & 63, r = blockIdx.x >> 6;   // same-XCD per batch
    const int tid = threadIdx.x;
    __shared__ float vin[K1PAD];       // [0:3]=x [3:63]=w [63:463]=h1 [463:470]=0
    __shared__ float h2l[CS], h1f[CS];
    __shared__ float cst[100], c2l[100];
    __shared__ float part[4000];
    __shared__ float biasl[400], bias2l[400];
    __shared__ float wwr[30 * 100];
    __shared__ float al[NK], be[NK], kap[NK], phi[NU + 1], bwl[30];
    __shared__ float ps[32];
    __shared__ ush chars[NU];
    __shared__ float tl;
    __shared__ unsigned woS[31 * 403];
    // LDS ~88 KB -> 1 block/CU, grid 256 = all resident

    const int ks = tid / 50, jt = tid % 50;
    const int k0a = ks * 47, k0b = ks * 40;
    const ush* wpa = W1P + (size_t)k0a * G4 + r * 400 + jt * 8;
    const ush* wpb = W2T + (size_t)(K2 + k0b) * G4 + r * 400 + jt * 8;
    const int jlo = r * 30, jcnt = (r == 3) ? 31 : 30;

    // ---- init
    for (int i = tid; i < 3000; i += 512) {
        int g = i / 100, k = i - g * 100;
        wwr[i] = Ww[g * 400 + r * 100 + k];
    }
    {
        const unsigned* WoB4 = (const unsigned*)WoB;
        for (int i = tid; i < jcnt * 400; i += 512) {
            int row = i / 400, col = i % 400;
            woS[row * 403 + col] = WoB4[(jlo + row) * 400 + col];
        }
    }
    if (tid < NU) {
        const float* ohr = onehots + (size_t)b * NU * NV + tid * NV;
        int c = 0;
        for (int v = 0; v < NV; ++v) if (ohr[v] > 0.5f) c = v;
        chars[tid] = (ush)c;
    }
    if (doA && t0A == 0 && r == 0) {   // x rows of Apan (once, fused(0))
        for (int i = tid; i < NT * 3; i += 512) {
            int tt = i / 3, c = i - tt * 3;
            Apan[((size_t)tt * NB + b) * APK + c] = f2h(x[(b * NT + tt) * 3 + c]);
        }
    }
    if (tid < 400) {
        int g = tid / 100, cl = tid % 100;
        biasl[tid]  = b1[g * 400 + r * 100 + cl];
        bias2l[tid] = b2[g * 400 + r * 100 + cl];
        if (doA) vin[63 + tid] = (t0A == 0) ? h10[b * CS + tid]
                                            : hx1[(size_t)((t0A - 1) & 1) * (NB * CS) + b * CS + tid];
        if (doS) h2l[tid] = (t0S == 0) ? h20[b * CS + tid]
                                       : hx2[(size_t)((t0S - 1) & 1) * (NB * CS) + b * CS + tid];
    }
    if (tid >= 400 && tid < 500) {
        if (doA) cst[tid - 400] = (t0A == 0) ? c10[b * CS + r * 100 + (tid - 400)]
                                             : st_c1[b * CS + r * 100 + (tid - 400)];
        if (doS) c2l[tid - 400] = (t0S == 0) ? c20[b * CS + r * 100 + (tid - 400)]
                                             : st_c2[b * CS + r * 100 + (tid - 400)];
    }
    if (doA) {
        if (tid < 60) vin[3 + tid] = (t0A == 0) ? w0[b * NV + tid] : st_w[b * NV + tid];
        if (tid >= 60 && tid < 70) kap[tid - 60] = (t0A == 0) ? kap0[b * NK + (tid - 60)]
                                                              : st_kap[b * NK + (tid - 60)];
        if (tid >= 70 && tid < 73) vin[tid - 70] = x[(b * NT + t0A) * 3 + (tid - 70)];
    }
    if (tid >= 73 && tid < 103) bwl[tid - 73] = bw[tid - 73];
    if (tid == 103) tl = text_lens[b];
    if (tid >= 104 && tid < 111) vin[463 + (tid - 104)] = 0.f;
    __syncthreads();

    for (int i = 0; i < TC; ++i) {
        const int tA = t0A + i, tS = t0S + i, hS = tS - 1;
        // P1: scan1 W1P stream
        if (doA && tid < 500) {
            float a0 = 0.f, a1 = 0.f, a2 = 0.f, a3 = 0.f, a4 = 0.f, a5 = 0.f, a6 = 0.f, a7 = 0.f;
            const ush* wp = wpa;
            #pragma unroll 4
            for (int kk = 0; kk < 47; ++kk, wp += G4) {
                float a_ = vin[k0a + kk];
                uint4 wv = *(const uint4*)wp;
                FMIX_LO(a0, wv.x, a_); FMIX_HI(a1, wv.x, a_);
                FMIX_LO(a2, wv.y, a_); FMIX_HI(a3, wv.y, a_);
                FMIX_LO(a4, wv.z, a_); FMIX_HI(a5, wv.z, a_);
                FMIX_LO(a6, wv.w, a_); FMIX_HI(a7, wv.w, a_);
            }
            float* pp = part + ks * 400 + jt;
            pp[0] = a0; pp[50] = a1; pp[100] = a2; pp[150] = a3;
            pp[200] = a4; pp[250] = a5; pp[300] = a6; pp[350] = a7;
        }
        __syncthreads();
        // P2: h1 cell + publish || stage h1f[hS] from Apan
        if (doA && tid < 100) {
            int j0 = tid, j1 = 100 + tid, j2 = 200 + tid, j3 = 300 + tid;
            int o0 = (j0 & 7) * 50 + (j0 >> 3), o1 = (j1 & 7) * 50 + (j1 >> 3);
            int o2 = (j2 & 7) * 50 + (j2 >> 3), o3 = (j3 & 7) * 50 + (j3 >> 3);
            float gi = biasl[j0], gf = biasl[j1], gg = biasl[j2], go = biasl[j3];
            #pragma unroll
            for (int q = 0; q < 10; ++q) {
                const float* pb = part + q * 400;
                gi += pb[o0]; gf += pb[o1]; gg += pb[o2]; go += pb[o3];
            }
            float c = sigm(gf) * cst[tid] + sigm(gi) * tanhf(gg);
            float h = sigm(go) * tanhf(c);
            cst[tid] = c;
            int ci = r * 100 + tid;
            vin[63 + ci] = h;
            __hip_atomic_store(&hx1[(size_t)(tA & 1) * (NB * CS) + b * CS + ci], h,
                               __ATOMIC_RELAXED, __HIP_MEMORY_SCOPE_AGENT);
            Apan[((size_t)tA * NB + b) * APK + 63 + ci] = f2h(h);
        } else if (doS && hS >= 0 && tid >= 100 && tid < 200) {
            #pragma unroll
            for (int q = 0; q < 4; ++q) {
                int k = (tid - 100) + q * 100;
                h1f[k] = h2f(Apan[((size_t)hS * NB + b) * APK + 63 + k]);
            }
        }
        __syncthreads();
        // P3: attention partials over own h1 slice
        if (doA && tid < 240) {
            int g = tid >> 3, l = tid & 7;
            const float* hl_ = vin + 63 + r * 100;
            const float* wr = wwr + g * 100;
            float s = 0.f;
            #pragma unroll
            for (int m = 0; m < 13; ++m) {
                int k = l + 8 * m;
                if (k < 100) s = fmaf(hl_[k], wr[k], s);
            }
            s += __shfl_down(s, 4, 8);
            s += __shfl_down(s, 2, 8);
            s += __shfl_down(s, 1, 8);
            if (l == 0)
                __hip_atomic_store(&hxp[(size_t)(tA & 1) * (NB * 128) + b * 128 + r * 32 + g], s,
                                   __ATOMIC_RELAXED, __HIP_MEMORY_SCOPE_AGENT);
        }
        asm volatile("s_waitcnt vmcnt(0)" ::: "memory");
        __syncthreads();
        // P4: global 4-block barrier (flag monotonic across launches)
        if (tid == 0) {
            __hip_atomic_fetch_add(&flg[b * FLGS], 1u, __ATOMIC_RELAXED, __HIP_MEMORY_SCOPE_AGENT);
            unsigned tgt = 4u * (unsigned)(t0A + i + 1);
            while (__hip_atomic_load(&flg[b * FLGS], __ATOMIC_RELAXED, __HIP_MEMORY_SCOPE_AGENT) < tgt)
                __builtin_amdgcn_s_sleep(1);
        }
        __syncthreads();
        // P5a: pull h1[tA] peers + combine attention
        if (doA) {
            if (tid < 400 && (tid / 100) != r) {
                vin[63 + tid] = __hip_atomic_load(&hx1[(size_t)(tA & 1) * (NB * CS) + b * CS + tid],
                                                  __ATOMIC_RELAXED, __HIP_MEMORY_SCOPE_AGENT);
            } else if (tid >= 448 && tid < 478) {
                int g = tid - 448;
                const float* pb = hxp + (size_t)(tA & 1) * (NB * 128) + b * 128;
                float s = __hip_atomic_load(&pb[g], __ATOMIC_RELAXED, __HIP_MEMORY_SCOPE_AGENT)
                        + __hip_atomic_load(&pb[32 + g], __ATOMIC_RELAXED, __HIP_MEMORY_SCOPE_AGENT)
                        + __hip_atomic_load(&pb[64 + g], __ATOMIC_RELAXED, __HIP_MEMORY_SCOPE_AGENT)
                        + __hip_atomic_load(&pb[96 + g], __ATOMIC_RELAXED, __HIP_MEMORY_SCOPE_AGENT);
                float pv = expf(s + bwl[g]);
                if (g < NK) al[g] = pv;
                else if (g < 2 * NK) be[g - NK] = pv;
                else kap[g - 2 * NK] += pv;
            }
        }
        __syncthreads();
        // P5b: pull h2[tS-1] peers || phi
        if (doS && tS > 0 && tid < 300) {
            int c = tid + ((tid / 100 >= r) ? 100 : 0);
            h2l[c] = __hip_atomic_load(&hx2[(size_t)((tS - 1) & 1) * (NB * CS) + b * CS + c],
                                       __ATOMIC_RELAXED, __HIP_MEMORY_SCOPE_AGENT);
        } else if (doA && tid >= 320 && tid <= 320 + NU) {
            int u = tid - 320;
            float uu = (float)u, s = 0.f;
            #pragma unroll
            for (int k = 0; k < NK; ++k) { float d = kap[k] - uu; s += al[k] * expf(-be[k] * d * d); }
            phi[u] = s * (80.f / tl);
        }
        __syncthreads();
        // P6: head(hS) over [h1f, h2l] || w gather
        if (doS && hS >= 0 && tid < 248) {
            int jj = tid >> 3, l = tid & 7;
            if (jj < jcnt) {
                const ush* wrow = (const ush*)(woS + jj * 403) + l * 100;
                const float* crow = (l < 4) ? (h1f + l * 100) : (h2l + (l - 4) * 100);
                float s = 0.f;
                #pragma unroll
                for (int i2 = 0; i2 < 50; ++i2) {
                    unsigned wv = *(const unsigned*)(wrow + 2 * i2);
                    float clo = crow[2 * i2], chi = crow[2 * i2 + 1];
                    FMIX_LO(s, wv, clo);
                    FMIX_HI(s, wv, chi);
                }
                s += __shfl_down(s, 4, 8);
                s += __shfl_down(s, 2, 8);
                s += __shfl_down(s, 1, 8);
                if (l == 0) ps[jj] = s + bo[jlo + jj];
            }
        } else if (doA && tid >= 256 && tid < 316) {
            int v = tid - 256;
            float s = 0.f;
            #pragma unroll 8
            for (int u = 0; u < NU; ++u)
                if (chars[u] == (ush)v) s += phi[u];
            vin[3 + v] = s;
            if (r == 0) {
                Apan[((size_t)tA * NB + b) * APK + 3 + v] = f2h(s);
                if (tA == NT - 1) outp[OFF_WOLD + b * NV + v] = s;
            }
        }
        __syncthreads();
        // P7: MDN out(hS) || final kap/phi at tA==599
        if (doS && hS >= 0 && tid < jcnt) {
            int j = jlo + tid;
            float v = ps[tid];
            const size_t nt_ = (size_t)b * NT + hS;
            if (j == 120) {
                outp[OFF_END + nt_] = sigm(v);
            } else if (j < 20) {
                float mx = -1e30f;
                #pragma unroll
                for (int m = 0; m < NM; ++m) mx = fmaxf(mx, ps[m]);
                float sm = 0.f;
                #pragma unroll
                for (int m = 0; m < NM; ++m) sm += expf(ps[m] - mx);
                outp[OFF_W + nt_ * NM + j] = expf(v - mx) / sm;
            } else {
                int sec = j / 20, idx = j - sec * 20;
                float o = (sec == 5) ? tanhf(v) : v;
                unsigned offs = (sec == 1) ? OFF_MU1 : (sec == 2) ? OFF_MU2 :
                                (sec == 3) ? OFF_LS1 : (sec == 4) ? OFF_LS2 : OFF_RHO;
                outp[offs + nt_ * NM + idx] = o;
            }
        }
        if (doA && tA == NT - 1 && r == 0) {
            if (tid >= 60 && tid < 70) outp[OFF_KAP + b * NK + (tid - 60)] = kap[tid - 60];
            if (tid >= 100 && tid <= 100 + NU) outp[OFF_PHI + b * (NU + 1) + (tid - 100)] = phi[tid - 100];
        }
        __syncthreads();
        // P8: scan2 hh stream over h2l (= h2[tS-1])
        if (doS && tid < 500) {
            float a0 = 0.f, a1 = 0.f, a2 = 0.f, a3 = 0.f, a4 = 0.f, a5 = 0.f, a6 = 0.f, a7 = 0.f;
            const ush* wp = wpb;
            #pragma unroll 4
            for (int kk = 0; kk < 40; ++kk, wp += G4) {
                float a_ = h2l[k0b + kk];
                uint4 wv = *(const uint4*)wp;
                FMIX_LO(a0, wv.x, a_); FMIX_HI(a1, wv.x, a_);
                FMIX_LO(a2, wv.y, a_); FMIX_HI(a3, wv.y, a_);
                FMIX_LO(a4, wv.z, a_); FMIX_HI(a5, wv.z, a_);
                FMIX_LO(a6, wv.w, a_); FMIX_HI(a7, wv.w, a_);
            }
            float* pp = part + ks * 400 + jt;
            pp[0] = a0; pp[50] = a1; pp[100] = a2; pp[150] = a3;
            pp[200] = a4; pp[250] = a5; pp[300] = a6; pp[350] = a7;
        }
        __syncthreads();
        // P9: h2 cell (+Z) + publish || x prefetch
        if (doS && tid < 100) {
            int j0 = tid, j1 = 100 + tid, j2 = 200 + tid, j3 = 300 + tid;
            int o0 = (j0 & 7) * 50 + (j0 >> 3), o1 = (j1 & 7) * 50 + (j1 >> 3);
            int o2 = (j2 & 7) * 50 + (j2 >> 3), o3 = (j3 & 7) * 50 + (j3 >> 3);
            const size_t zb = ((size_t)i * NB + b) * G4;
            int cbase = r * 100 + tid;
            float gi = bias2l[j0] + h2f(Zb[zb + 0 * CS + cbase]);
            float gf = bias2l[j1] + h2f(Zb[zb + 1 * CS + cbase]);
            float gg = bias2l[j2] + h2f(Zb[zb + 2 * CS + cbase]);
            float go = bias2l[j3] + h2f(Zb[zb + 3 * CS + cbase]);
            #pragma unroll
            for (int q = 0; q < 10; ++q) {
                const float* pb = part + q * 400;
                gi += pb[o0]; gf += pb[o1]; gg += pb[o2]; go += pb[o3];
            }
            float c = sigm(gf) * c2l[tid] + sigm(gi) * tanhf(gg);
            float h = sigm(go) * tanhf(c);
            c2l[tid] = c;
            h2l[cbase] = h;
            __hip_atomic_store(&hx2[(size_t)(tS & 1) * (NB * CS) + b * CS + cbase], h,
                               __ATOMIC_RELAXED, __HIP_MEMORY_SCOPE_AGENT);
        } else if (doA && tid >= 100 && tid < 103) {
            if (tA + 1 < NT) vin[tid - 100] = x[(b * NT + tA + 1) * 3 + (tid - 100)];
        }
        __syncthreads();
    }

    // ---- carry state to next launch
    if (doA && !lastA) {
        if (tid < 100) st_c1[b * CS + r * 100 + tid] = cst[tid];
        if (r == 0) {
            if (tid >= 128 && tid < 188) st_w[b * NV + (tid - 128)] = vin[3 + tid - 128];
            if (tid >= 192 && tid < 202) st_kap[b * NK + (tid - 192)] = kap[tid - 192];
        }
    }
    if (lastA) {
        if (tid < 100) outp[OFF_C1 + b * CS + r * 100 + tid] = cst[tid];
        if (r == 0 && tid >= 112 && tid < 512) outp[OFF_H1 + b * CS + (tid - 112)] = vin[63 + tid - 112];
    }
    if (doS && !lastS) {
        if (tid < 100) st_c2[b * CS + r * 100 + tid] = c2l[tid];
    }
    if (lastS) {   // flush: barrier round, pull h2[599], head(599), outputs
        asm volatile("s_waitcnt vmcnt(0)" ::: "memory");
        __syncthreads();
        if (tid == 0) {
            __hip_atomic_fetch_add(&flg[b * FLGS], 1u, __ATOMIC_RELAXED, __HIP_MEMORY_SCOPE_AGENT);
            unsigned tgt = 4u * (unsigned)(t0A + TC + 1);
            while (__hip_atomic_load(&flg[b * FLGS], __ATOMIC_RELAXED, __HIP_MEMORY_SCOPE_AGENT) < tgt)
                __builtin_amdgcn_s_sleep(1);
        }
        __syncthreads();
        if (tid < 300) {
            int c = tid + ((tid / 100 >= r) ? 100 : 0);
            h2l[c] = __hip_atomic_load(&hx2[(size_t)((NT - 1) & 1) * (NB * CS) + b * CS + c],
                                       __ATOMIC_RELAXED, __HIP_MEMORY_SCOPE_AGENT);
        } else if (tid >= 300 && tid < 400) {
            #pragma unroll
            for (int q = 0; q < 4; ++q) {
                int k = (tid - 300) + q * 100;
                h1f[k] = h2f(Apan[((size_t)(NT - 1) * NB + b) * APK + 63 + k]);
            }
        }
        __syncthreads();
        if (tid < 248) {
            int jj = tid >> 3, l = tid & 7;
            if (jj < jcnt) {
                const ush* wrow = (const ush*)(woS + jj * 403) + l * 100;
                const float* crow = (l < 4) ? (h1f + l * 100) : (h2l + (l - 4) * 100);
                float s = 0.f;
                #pragma unroll
                for (int i2 = 0; i2 < 50; ++i2) {
                    unsigned wv = *(const unsigned*)(wrow + 2 * i2);
                    float clo = crow[2 * i2], chi = crow[2 * i2 + 1];
                    FMIX_LO(s, wv, clo);
                    FMIX_HI(s, wv, chi);
                }
                s += __shfl_down(s, 4, 8);
                s += __shfl_down(s, 2, 8);
                s += __shfl_down(s, 1, 8);
                if (l == 0) ps[jj] = s + bo[jlo + jj];
            }
        }
        __syncthreads();
        if (tid < jcnt) {
            int j = jlo + tid;
            float v = ps[tid];
            const size_t nt_ = (size_t)b * NT + (NT - 1);
            if (j == 120) {
                outp[OFF_END + nt_] = sigm(v);
            } else if (j < 20) {
                float mx = -1e30f;
                #pragma unroll
                for (int m = 0; m < NM; ++m) mx = fmaxf(mx, ps[m]);
                float sm = 0.f;
                #pragma unroll
                for (int m = 0; m < NM; ++m) sm += expf(ps[m] - mx);
                outp[OFF_W + nt_ * NM + j] = expf(v - mx) / sm;
            } else {
                int sec = j / 20, idx = j - sec * 20;
                float o = (sec == 5) ? tanhf(v) : v;
                unsigned offs = (sec == 1) ? OFF_MU1 : (sec == 2) ? OFF_MU2 :
                                (sec == 3) ? OFF_LS1 : (sec == 4) ? OFF_LS2 : OFF_RHO;
                outp[offs + nt_ * NM + idx] = o;
            }
        }
        if (tid < 100) outp[OFF_C2 + b * CS + r * 100 + tid] = c2l[tid];
        if (r == 0 && tid >= 112 && tid < 512) outp[OFF_H2 + b * CS + (tid - 112)] = h2l[tid - 112];
    }
}

// ---------------------------------------------------------------- Z = Apan @ W2_ih.T + b2 (128x64 tile, chunk of TC steps)
__global__ __launch_bounds__(256) void gemmZ_k(
    const ush* __restrict__ Apan, const ush* __restrict__ W2T, const float* __restrict__ b2,
    ush* __restrict__ Z, int n0) {
    __shared__ float As[32][130];
    __shared__ float Bs[32][65];
    const int tid = threadIdx.x;
    const int jt = blockIdx.x * 64;
    const int nt = blockIdx.y * 128;
    const int tx = tid & 15, ty = tid >> 4;
    float acc[8][4] = {};
    for (int k0 = 0; k0 < 480; k0 += 32) {
        #pragma unroll
        for (int rep = 0; rep < 2; ++rep) {
            int i = tid + rep * 256;
            int row = i >> 2, kq = (i & 3) * 8;
            uint4 av = *(const uint4*)(Apan + (size_t)(n0 + nt + row) * APK + k0 + kq);
            As[kq + 0][row] = hlo(av.x); As[kq + 1][row] = hhi(av.x);
            As[kq + 2][row] = hlo(av.y); As[kq + 3][row] = hhi(av.y);
            As[kq + 4][row] = hlo(av.z); As[kq + 5][row] = hhi(av.z);
            As[kq + 6][row] = hlo(av.w); As[kq + 7][row] = hhi(av.w);
        }
        {
            int kk = tid >> 3, j8 = (tid & 7) * 8;
            int k = k0 + kk;
            if (k < K2) {
                uint4 wv = *(const uint4*)(W2T + (size_t)k * G4 + jt + j8);
                Bs[kk][j8 + 0] = hlo(wv.x); Bs[kk][j8 + 1] = hhi(wv.x);
                Bs[kk][j8 + 2] = hlo(wv.y); Bs[kk][j8 + 3] = hhi(wv.y);
                Bs[kk][j8 + 4] = hlo(wv.z); Bs[kk][j8 + 5] = hhi(wv.z);
                Bs[kk][j8 + 6] = hlo(wv.w); Bs[kk][j8 + 7] = hhi(wv.w);
            } else {
                #pragma unroll
                for (int rr = 0; rr < 8; ++rr) Bs[kk][j8 + rr] = 0.f;
            }
        }
        __syncthreads();
        #pragma unroll 8
        for (int kk = 0; kk < 32; ++kk) {
            float c0 = Bs[kk][tx * 4 + 0], c1 = Bs[kk][tx * 4 + 1];
            float c2 = Bs[kk][tx * 4 + 2], c3 = Bs[kk][tx * 4 + 3];
            #pragma unroll
            for (int rr = 0; rr < 8; ++rr) {
                float a_ = As[kk][ty * 8 + rr];
                acc[rr][0] = fmaf(a_, c0, acc[rr][0]);
                acc[rr][1] = fmaf(a_, c1, acc[rr][1]);
                acc[rr][2] = fmaf(a_, c2, acc[rr][2]);
                acc[rr][3] = fmaf(a_, c3, acc[rr][3]);
            }
        }
        __syncthreads();
    }
    #pragma unroll
    for (int rr = 0; rr < 8; ++rr) {
        int n = nt + ty * 8 + rr;
        #pragma unroll
        for (int c = 0; c < 4; ++c) {
            int j = jt + tx * 4 + c;
            Z[(size_t)n * G4 + j] = f2h(acc[rr][c] + b2[j]);
        }
    }
}

// ---------------------------------------------------------------- launch
extern "C" void kernel_launch(void* const* d_in, const int* in_sizes, int n_in,
                              void* d_out, int out_size, void* d_ws, size_t ws_size,
                              hipStream_t stream) {
    const float* x    = (const float*)d_in[0];
    const float* oh   = (const float*)d_in[1];
    const float* tl   = (const float*)d_in[2];
    const float* w0   = (const float*)d_in[3];
    const float* kp0  = (const float*)d_in[4];
    const float* h10  = (const float*)d_in[5];
    const float* c10  = (const float*)d_in[6];
    const float* h20  = (const float*)d_in[7];
    const float* c20  = (const float*)d_in[8];
    const float* W1ih = (const float*)d_in[9];
    const float* W1hh = (const float*)d_in[10];
    const float* b1   = (const float*)d_in[11];
    const float* Ww   = (const float*)d_in[12];
    const float* bw   = (const float*)d_in[13];
    const float* W2ih = (const float*)d_in[14];
    const float* W2hh = (const float*)d_in[15];
    const float* b2   = (const float*)d_in[16];
    const float* Wo   = (const float*)d_in[17];
    const float* bo   = (const float*)d_in[18];
    float* outp = (float*)d_out;

    char* p = (char*)d_ws;
    auto alloc = [&](size_t bytes) { char* r = p; p += (bytes + 255) & ~(size_t)255; return r; };
    ush*   W1P  = (ush*)  alloc((size_t)K1PAD * G4 * 2);
    ush*   W2T  = (ush*)  alloc((size_t)863 * G4 * 2);
    ush*   WoB  = (ush*)  alloc((size_t)NP * CAT * 2);
    ush*   Apan = (ush*)  alloc((size_t)NT * NB * APK * 2);
    ush*   Zb   = (ush*)  alloc((size_t)TC * NB * G4 * 2);
    float* hx1  = (float*)alloc((size_t)2 * NB * CS * 4);
    float* hx2  = (float*)alloc((size_t)2 * NB * CS * 4);
    float* hxp  = (float*)alloc((size_t)2 * NB * 128 * 4);
    float* st_c1 = (float*)alloc((size_t)NB * CS * 4);
    float* st_c2 = (float*)alloc((size_t)NB * CS * 4);
    float* st_w  = (float*)alloc((size_t)NB * NV * 4);
    float* st_kap = (float*)alloc((size_t)NB * NK * 4);
    unsigned* flg = (unsigned*)alloc((size_t)NB * FLGS * 4);

    hipMemsetAsync(flg, 0, (size_t)NB * FLGS * 4, stream);
    hipMemsetAsync(Apan, 0, (size_t)NT * NB * APK * 2, stream);
    prep_k<<<(863 * G4 + 255) / 256, 256, 0, stream>>>(W1ih, W1hh, W2ih, W2hh, Wo,
                                                       W1P, W2T, WoB);
    const int NC = NT / TC;   // 6
    for (int c = 0; c <= NC; ++c) {
        int t0A = c * TC, t0S = (c - 1) * TC;
        int doA = (c < NC), doS = (c >= 1);
        fused_k<<<4 * NB, 512, 0, stream>>>(
            x, oh, tl, w0, kp0, h10, c10, h20, c20, b1, b2, Ww, bw, bo,
            W1P, W2T, WoB, Zb, Apan, outp, hx1, hx2, hxp, flg,
            st_c1, st_c2, st_w, st_kap,
            t0A, t0S, doA, doS, (c == NC - 1), (c == NC));
        if (doA) {
            gemmZ_k<<<dim3(G4 / 64, TC * NB / 128), 256, 0, stream>>>(
                Apan, W2T, b2, Zb, t0A * NB);
        }
    }
}

// Round 20
// 8263.929 us; speedup vs baseline: 4.5304x; 1.8606x over previous
//
#include <hip/hip_runtime.h>
#include <hip/hip_fp16.h>
#include <cstdint>
#include <cstddef>

#define NB 64
#define NT 600
#define NU 80
#define NV 60
#define CS 400
#define NK 10
#define NM 20
#define G4 1600      // 4*CS
#define K1 463       // 63 + 400
#define K1PAD 470    // 10 slices x 47
#define K2 463
#define NP 121
#define CAT 800
#define APK 480      // A-panel row stride (f16): [x(3), w(60), h1(400), pad(17)=0]
#define FLGS 64      // flag stride (unsigned) = 256 B -> one line per batch

#define OFF_END  0u
#define OFF_W    38400u
#define OFF_MU1  806400u
#define OFF_MU2  1574400u
#define OFF_LS1  2342400u
#define OFF_LS2  3110400u
#define OFF_RHO  3878400u
#define OFF_WOLD 4646400u
#define OFF_KAP  4650240u
#define OFF_H1   4650880u
#define OFF_C1   4676480u
#define OFF_H2   4702080u
#define OFF_C2   4727680u
#define OFF_PHI  4753280u

typedef unsigned short ush;

__device__ __forceinline__ float sigm(float v) { return 1.f / (1.f + expf(-v)); }
__device__ __forceinline__ float hlo(unsigned u) { return __half2float(__ushort_as_half((ush)(u & 0xffffu))); }
__device__ __forceinline__ float hhi(unsigned u) { return __half2float(__ushort_as_half((ush)(u >> 16))); }
__device__ __forceinline__ float h2f(ush v) { return __half2float(__ushort_as_half(v)); }
__device__ __forceinline__ ush f2h(float f) { return __half_as_ushort(__float2half_rn(f)); }

// guaranteed v_fma_mix_f32: acc += f16(lo/hi of w32) * a   (1 instruction per MAC)
#define FMIX_LO(acc, w32, a) asm("v_fma_mix_f32 %0, %1, %2, %0 op_sel_hi:[1,0,0]" : "+v"(acc) : "v"(w32), "v"(a))
#define FMIX_HI(acc, w32, a) asm("v_fma_mix_f32 %0, %1, %2, %0 op_sel:[1,0,0] op_sel_hi:[1,0,0]" : "+v"(acc) : "v"(w32), "v"(a))

// ---------------------------------------------------------------- prep
// W1P[k][jn] f16, jn = r*400 + g*100 + cl  <->  orig j = g*400 + r*100 + cl; rows 463..469 zero
// W2T: rows <463 = ih ORIGINAL j (gemmZ); rows 463..862 = hh PERMUTED jn (scan2)
__global__ void prep_k(const float* __restrict__ W1ih, const float* __restrict__ W1hh,
                       const float* __restrict__ W2ih, const float* __restrict__ W2hh,
                       const float* __restrict__ Wo,
                       ush* __restrict__ W1P, ush* __restrict__ W2T,
                       ush* __restrict__ WoB) {
    int i = blockIdx.x * blockDim.x + threadIdx.x;
    if (i < K1PAD * G4) {
        int k = i / G4, jn = i % G4;
        int r = jn / 400, q = jn % 400, g = q / 100, cl = q % 100;
        int j = g * 400 + r * 100 + cl;
        float v = (k < 63) ? W1ih[j * 63 + k] : (k < K1) ? W1hh[j * CS + (k - 63)] : 0.f;
        W1P[i] = f2h(v);
    }
    if (i < 863 * G4) {
        int k = i / G4, jj = i % G4;
        float v;
        if (k < K2) {
            v = W2ih[jj * K2 + k];
        } else {
            int r = jj / 400, q = jj % 400, g = q / 100, cl = q % 100;
            int j = g * 400 + r * 100 + cl;
            v = W2hh[j * CS + (k - K2)];
        }
        W2T[i] = f2h(v);
    }
    if (i < NP * CAT) WoB[i] = f2h(Wo[i]);
}

// ---------------------------------------------------------------- scan1: 4 blocks/batch (same XCD), streamed f16 weights
// attention k-split: pre-barrier partial dots over own h-slice; post-barrier 30-thread combine
__global__ __launch_bounds__(512, 2) void scan1_k(
    const float* __restrict__ x, const float* __restrict__ onehots,
    const float* __restrict__ text_lens, const float* __restrict__ w0,
    const float* __restrict__ kap0, const float* __restrict__ h10,
    const float* __restrict__ c10, const float* __restrict__ b1,
    const float* __restrict__ Ww, const float* __restrict__ bw,
    const ush* __restrict__ W1P,
    ush* __restrict__ Apan, float* __restrict__ outp,
    float* __restrict__ hx, float* __restrict__ hxp, unsigned* __restrict__ flg) {
    const int b = blockIdx.x & 63, r = blockIdx.x >> 6;   // blocks {b,b+64,b+128,b+192} on XCD b%8
    const int tid = threadIdx.x;
    __shared__ float inp[K1PAD];       // [0:3]=x_t [3:63]=w [63:463]=h1 [463:470]=0
    __shared__ float cst[100];
    __shared__ float part[4000];       // [ks*400 + rr*50 + jt], jn = jt*8+rr
    __shared__ float oh[NU * NV];
    __shared__ float wwl[30 * 400];
    __shared__ float biasl[400];
    __shared__ float al[NK], be[NK], kap[NK], phi[NU + 1], bwl[30];
    __shared__ float tl;
    // LDS ~88 KB (oh+wwl naturally referenced) -> 1 block/CU

    const int ks = tid / 50;           // 0..9 for tid<500
    const int jt = tid % 50;
    const int k0 = ks * 47;
    const ush* wp0 = W1P + (size_t)k0 * G4 + r * 400 + jt * 8;

    for (int i = tid; i < NU * NV; i += 512) oh[i] = onehots[b * NU * NV + i];
    for (int i = tid; i < 12000; i += 512) wwl[i] = Ww[i];
    if (r == 0) {                      // x rows of the A panel (pure input, once)
        for (int i = tid; i < NT * 3; i += 512) {
            int tt = i / 3, c = i - tt * 3;
            Apan[((size_t)tt * NB + b) * APK + c] = f2h(x[(b * NT + tt) * 3 + c]);
        }
    }
    if (tid < 400) {
        int g = tid / 100, cl = tid % 100;
        biasl[tid] = b1[g * 400 + r * 100 + cl];
        inp[63 + tid] = h10[b * CS + tid];
    }
    if (tid >= 400 && tid < 500) cst[tid - 400] = c10[b * CS + r * 100 + (tid - 400)];
    if (tid < 60) inp[3 + tid] = w0[b * NV + tid];
    if (tid >= 60 && tid < 70) kap[tid - 60] = kap0[b * NK + (tid - 60)];
    if (tid >= 70 && tid < 73) inp[tid - 70] = x[(b * NT + 0) * 3 + (tid - 70)];
    if (tid >= 73 && tid < 103) bwl[tid - 73] = bw[tid - 73];
    if (tid == 103) tl = text_lens[b];
    if (tid >= 104 && tid < 111) inp[463 + (tid - 104)] = 0.f;
    __syncthreads();

    for (int t = 0; t < NT; ++t) {
        // s1: gate partials — stream f16 weights from L2, v_fma_mix (1 inst/MAC)
        if (tid < 500) {
            float a0 = 0.f, a1 = 0.f, a2 = 0.f, a3 = 0.f, a4 = 0.f, a5 = 0.f, a6 = 0.f, a7 = 0.f;
            const ush* wp = wp0;
            #pragma unroll 4
            for (int kk = 0; kk < 47; ++kk, wp += G4) {
                float a_ = inp[k0 + kk];
                uint4 wv = *(const uint4*)wp;
                FMIX_LO(a0, wv.x, a_); FMIX_HI(a1, wv.x, a_);
                FMIX_LO(a2, wv.y, a_); FMIX_HI(a3, wv.y, a_);
                FMIX_LO(a4, wv.z, a_); FMIX_HI(a5, wv.z, a_);
                FMIX_LO(a6, wv.w, a_); FMIX_HI(a7, wv.w, a_);
            }
            float* pp = part + ks * 400 + jt;
            pp[0] = a0; pp[50] = a1; pp[100] = a2; pp[150] = a3;
            pp[200] = a4; pp[250] = a5; pp[300] = a6; pp[350] = a7;
        }
        __syncthreads();
        // merged reduce + cell update (own 100 cells) + publish h
        if (tid < 100) {
            int j0 = tid, j1 = 100 + tid, j2 = 200 + tid, j3 = 300 + tid;
            int o0 = (j0 & 7) * 50 + (j0 >> 3), o1 = (j1 & 7) * 50 + (j1 >> 3);
            int o2 = (j2 & 7) * 50 + (j2 >> 3), o3 = (j3 & 7) * 50 + (j3 >> 3);
            float gi = biasl[j0], gf = biasl[j1], gg = biasl[j2], go = biasl[j3];
            #pragma unroll
            for (int q = 0; q < 10; ++q) {
                const float* pb = part + q * 400;
                gi += pb[o0]; gf += pb[o1]; gg += pb[o2]; go += pb[o3];
            }
            float c = sigm(gf) * cst[tid] + sigm(gi) * tanhf(gg);
            float h = sigm(go) * tanhf(c);
            cst[tid] = c;
            int ci = r * 100 + tid;
            inp[63 + ci] = h;
            __hip_atomic_store(&hx[(size_t)(t & 1) * (NB * CS) + b * CS + ci], h,
                               __ATOMIC_RELAXED, __HIP_MEMORY_SCOPE_AGENT);
            Apan[((size_t)t * NB + b) * APK + 63 + ci] = f2h(h);
        }
        __syncthreads();
        // pp: attention partials over OWN h slice (pre-barrier); publish 30 floats
        if (tid < 240) {
            int g = tid >> 3, l = tid & 7;
            const float* hl_ = inp + 63 + r * 100;
            const float* wr = wwl + g * 400 + r * 100;
            float s = 0.f;
            #pragma unroll
            for (int m = 0; m < 13; ++m) {
                int k = l + 8 * m;
                if (k < 100) s = fmaf(hl_[k], wr[k], s);
            }
            s += __shfl_down(s, 4, 8);
            s += __shfl_down(s, 2, 8);
            s += __shfl_down(s, 1, 8);
            if (l == 0)
                __hip_atomic_store(&hxp[(size_t)(t & 1) * (NB * 128) + b * 128 + r * 32 + g], s,
                                   __ATOMIC_RELAXED, __HIP_MEMORY_SCOPE_AGENT);
        } else if (tid >= 256 && tid < 259) {
            if (t + 1 < NT) inp[tid - 256] = x[(b * NT + t + 1) * 3 + (tid - 256)];
        }
        asm volatile("s_waitcnt vmcnt(0)" ::: "memory");
        __syncthreads();
        if (tid == 0) {
            __hip_atomic_fetch_add(&flg[b * FLGS], 1u, __ATOMIC_RELAXED, __HIP_MEMORY_SCOPE_AGENT);
            unsigned tgt = 4u * (unsigned)(t + 1);
            while (__hip_atomic_load(&flg[b * FLGS], __ATOMIC_RELAXED, __HIP_MEMORY_SCOPE_AGENT) < tgt)
                __builtin_amdgcn_s_sleep(1);
        }
        __syncthreads();
        // pull peer h slices (XCD-local) + combine attention partials
        if (tid < 400 && (tid / 100) != r) {
            inp[63 + tid] = __hip_atomic_load(&hx[(size_t)(t & 1) * (NB * CS) + b * CS + tid],
                                              __ATOMIC_RELAXED, __HIP_MEMORY_SCOPE_AGENT);
        } else if (tid >= 448 && tid < 478) {
            int g = tid - 448;
            const float* pb = hxp + (size_t)(t & 1) * (NB * 128) + b * 128;
            float s = __hip_atomic_load(&pb[g], __ATOMIC_RELAXED, __HIP_MEMORY_SCOPE_AGENT)
                    + __hip_atomic_load(&pb[32 + g], __ATOMIC_RELAXED, __HIP_MEMORY_SCOPE_AGENT)
                    + __hip_atomic_load(&pb[64 + g], __ATOMIC_RELAXED, __HIP_MEMORY_SCOPE_AGENT)
                    + __hip_atomic_load(&pb[96 + g], __ATOMIC_RELAXED, __HIP_MEMORY_SCOPE_AGENT);
            float pv = expf(s + bwl[g]);
            if (g < NK) al[g] = pv;
            else if (g < 2 * NK) be[g - NK] = pv;
            else kap[g - 2 * NK] += pv;
        }
        __syncthreads();
        if (tid <= NU) {
            float u = (float)tid, s = 0.f;
            #pragma unroll
            for (int k = 0; k < NK; ++k) { float d = kap[k] - u; s += al[k] * expf(-be[k] * d * d); }
            phi[tid] = s * (80.f / tl);
        }
        __syncthreads();
        // w: 480 threads (60 v x 8 u-slices of 10)
        if (tid < 480) {
            int v = tid >> 3, l = tid & 7;
            const float* ohp = oh + (l * 10) * NV + v;
            float s = 0.f;
            #pragma unroll
            for (int u = 0; u < 10; ++u) s = fmaf(phi[l * 10 + u], ohp[u * NV], s);
            s += __shfl_down(s, 4, 8);
            s += __shfl_down(s, 2, 8);
            s += __shfl_down(s, 1, 8);
            if (l == 0) {
                inp[3 + v] = s;
                if (r == 0) Apan[((size_t)t * NB + b) * APK + 3 + v] = f2h(s);
            }
        }
        __syncthreads();
    }
    if (tid < 100) outp[OFF_C1 + b * CS + r * 100 + tid] = cst[tid];
    if (r == 0) {
        if (tid < 400) outp[OFF_H1 + b * CS + tid] = inp[63 + tid];
        if (tid < 60) outp[OFF_WOLD + b * NV + tid] = inp[3 + tid];
        if (tid >= 60 && tid < 70) outp[OFF_KAP + b * NK + (tid - 60)] = kap[tid - 60];
        if (tid >= 100 && tid <= 100 + NU) outp[OFF_PHI + b * (NU + 1) + (tid - 100)] = phi[tid - 100];
    }
}

// ---------------------------------------------------------------- Z = Apan @ W2_ih.T + b2 (128x64 tile)
__global__ __launch_bounds__(256) void gemmZ_k(
    const ush* __restrict__ Apan, const ush* __restrict__ W2T, const float* __restrict__ b2,
    ush* __restrict__ Z, int n0) {
    __shared__ float As[32][130];
    __shared__ float Bs[32][65];
    const int tid = threadIdx.x;
    const int jt = blockIdx.x * 64;
    const int nt = blockIdx.y * 128;
    const int tx = tid & 15, ty = tid >> 4;
    float acc[8][4] = {};
    for (int k0 = 0; k0 < 480; k0 += 32) {
        #pragma unroll
        for (int rep = 0; rep < 2; ++rep) {   // A tile: 128 rows, 1 uint4/thread/rep
            int i = tid + rep * 256;
            int row = i >> 2, kq = (i & 3) * 8;
            uint4 av = *(const uint4*)(Apan + (size_t)(n0 + nt + row) * APK + k0 + kq);
            As[kq + 0][row] = hlo(av.x); As[kq + 1][row] = hhi(av.x);
            As[kq + 2][row] = hlo(av.y); As[kq + 3][row] = hhi(av.y);
            As[kq + 4][row] = hlo(av.z); As[kq + 5][row] = hhi(av.z);
            As[kq + 6][row] = hlo(av.w); As[kq + 7][row] = hhi(av.w);
        }
        {
            int kk = tid >> 3, j8 = (tid & 7) * 8;
            int k = k0 + kk;
            if (k < K2) {
                uint4 wv = *(const uint4*)(W2T + (size_t)k * G4 + jt + j8);
                Bs[kk][j8 + 0] = hlo(wv.x); Bs[kk][j8 + 1] = hhi(wv.x);
                Bs[kk][j8 + 2] = hlo(wv.y); Bs[kk][j8 + 3] = hhi(wv.y);
                Bs[kk][j8 + 4] = hlo(wv.z); Bs[kk][j8 + 5] = hhi(wv.z);
                Bs[kk][j8 + 6] = hlo(wv.w); Bs[kk][j8 + 7] = hhi(wv.w);
            } else {
                #pragma unroll
                for (int rr = 0; rr < 8; ++rr) Bs[kk][j8 + rr] = 0.f;
            }
        }
        __syncthreads();
        #pragma unroll 8
        for (int kk = 0; kk < 32; ++kk) {
            float c0 = Bs[kk][tx * 4 + 0], c1 = Bs[kk][tx * 4 + 1];
            float c2 = Bs[kk][tx * 4 + 2], c3 = Bs[kk][tx * 4 + 3];
            #pragma unroll
            for (int rr = 0; rr < 8; ++rr) {
                float a_ = As[kk][ty * 8 + rr];
                acc[rr][0] = fmaf(a_, c0, acc[rr][0]);
                acc[rr][1] = fmaf(a_, c1, acc[rr][1]);
                acc[rr][2] = fmaf(a_, c2, acc[rr][2]);
                acc[rr][3] = fmaf(a_, c3, acc[rr][3]);
            }
        }
        __syncthreads();
    }
    #pragma unroll
    for (int rr = 0; rr < 8; ++rr) {
        int n = nt + ty * 8 + rr;
        #pragma unroll
        for (int c = 0; c < 4; ++c) {
            int j = jt + tx * 4 + c;
            Z[(size_t)n * G4 + j] = f2h(acc[rr][c] + b2[j]);
        }
    }
}

// ---------------------------------------------------------------- scan2: 4 blocks/batch (same XCD), streamed f16 hh
__global__ __launch_bounds__(512, 2) void scan2_k(
    const ush* __restrict__ Z, const ush* __restrict__ W2T, const ush* __restrict__ WoB,
    const ush* __restrict__ Apan, const float* __restrict__ bo,
    const float* __restrict__ h20, const float* __restrict__ c20,
    float* __restrict__ h2st, float* __restrict__ c2st,
    float* __restrict__ outp, float* __restrict__ hx2, unsigned* __restrict__ flg2,
    int t0, int tc, int first, int last) {
    const int b = blockIdx.x & 63, r = blockIdx.x >> 6;
    const int tid = threadIdx.x;
    __shared__ float h2l[CS], c2l[100], h1f[CS];
    __shared__ float part[4000];
    __shared__ float ps[32];
    __shared__ unsigned woS[31 * 520];   // own Wo j-slice; stride 520 pads LDS >80 KB -> 1 block/CU
    const int jlo = r * 30, jcnt = (r == 3) ? 31 : 30;

    const int ks = tid / 50, jt = tid % 50;
    const int k0 = ks * 40;
    const ush* wp0 = W2T + (size_t)(K2 + k0) * G4 + r * 400 + jt * 8;

    {
        const unsigned* WoB4 = (const unsigned*)WoB;
        for (int i = tid; i < jcnt * 400; i += 512) {
            int row = i / 400, col = i % 400;
            woS[row * 520 + col] = WoB4[(jlo + row) * 400 + col];
        }
    }
    if (tid < 400) h2l[tid] = first ? h20[b * CS + tid] : h2st[b * CS + tid];
    if (tid >= 400 && tid < 500)
        c2l[tid - 400] = first ? c20[b * CS + r * 100 + (tid - 400)]
                               : c2st[b * CS + r * 100 + (tid - 400)];
    __syncthreads();

    for (int ti = 0; ti < tc; ++ti) {
        const int gt = t0 + ti;
        // s1: hh gate partials — stream f16 weights from L2, v_fma_mix
        if (tid < 500) {
            float a0 = 0.f, a1 = 0.f, a2 = 0.f, a3 = 0.f, a4 = 0.f, a5 = 0.f, a6 = 0.f, a7 = 0.f;
            const ush* wp = wp0;
            #pragma unroll 4
            for (int kk = 0; kk < 40; ++kk, wp += G4) {
                float a_ = h2l[k0 + kk];
                uint4 wv = *(const uint4*)wp;
                FMIX_LO(a0, wv.x, a_); FMIX_HI(a1, wv.x, a_);
                FMIX_LO(a2, wv.y, a_); FMIX_HI(a3, wv.y, a_);
                FMIX_LO(a4, wv.z, a_); FMIX_HI(a5, wv.z, a_);
                FMIX_LO(a6, wv.w, a_); FMIX_HI(a7, wv.w, a_);
            }
            float* pp = part + ks * 400 + jt;
            pp[0] = a0; pp[50] = a1; pp[100] = a2; pp[150] = a3;
            pp[200] = a4; pp[250] = a5; pp[300] = a6; pp[350] = a7;
        }
        __syncthreads();
        // merged reduce + Z + cell; threads 400-499 stage h1f
        if (tid < 100) {
            int j0 = tid, j1 = 100 + tid, j2 = 200 + tid, j3 = 300 + tid;
            int o0 = (j0 & 7) * 50 + (j0 >> 3), o1 = (j1 & 7) * 50 + (j1 >> 3);
            int o2 = (j2 & 7) * 50 + (j2 >> 3), o3 = (j3 & 7) * 50 + (j3 >> 3);
            const size_t zb = ((size_t)ti * NB + b) * G4;
            int cbase = r * 100 + tid;
            float gi = h2f(Z[zb + 0 * CS + cbase]);
            float gf = h2f(Z[zb + 1 * CS + cbase]);
            float gg = h2f(Z[zb + 2 * CS + cbase]);
            float go = h2f(Z[zb + 3 * CS + cbase]);
            #pragma unroll
            for (int q = 0; q < 10; ++q) {
                const float* pb = part + q * 400;
                gi += pb[o0]; gf += pb[o1]; gg += pb[o2]; go += pb[o3];
            }
            float c = sigm(gf) * c2l[tid] + sigm(gi) * tanhf(gg);
            float h = sigm(go) * tanhf(c);
            c2l[tid] = c;
            h2l[cbase] = h;
            __hip_atomic_store(&hx2[(size_t)(gt & 1) * (NB * CS) + b * CS + cbase], h,
                               __ATOMIC_RELAXED, __HIP_MEMORY_SCOPE_AGENT);
        } else if (tid >= 400 && tid < 500) {
            #pragma unroll
            for (int q = 0; q < 4; ++q) {
                int k = (tid - 400) + q * 100;
                h1f[k] = h2f(Apan[((size_t)gt * NB + b) * APK + 63 + k]);
            }
        }
        asm volatile("s_waitcnt vmcnt(0)" ::: "memory");
        __syncthreads();
        if (tid == 0) {
            __hip_atomic_fetch_add(&flg2[b * FLGS], 1u, __ATOMIC_RELAXED, __HIP_MEMORY_SCOPE_AGENT);
            unsigned tgt = 4u * (unsigned)(gt + 1);
            while (__hip_atomic_load(&flg2[b * FLGS], __ATOMIC_RELAXED, __HIP_MEMORY_SCOPE_AGENT) < tgt)
                __builtin_amdgcn_s_sleep(1);
        }
        __syncthreads();
        if (tid < 400 && (tid / 100) != r) {
            h2l[tid] = __hip_atomic_load(&hx2[(size_t)(gt & 1) * (NB * CS) + b * CS + tid],
                                         __ATOMIC_RELAXED, __HIP_MEMORY_SCOPE_AGENT);
        }
        __syncthreads();
        // head: own j-slice [jlo, jlo+jcnt), 16 lanes per j
        if (tid < jcnt * 16) {
            int jj = tid >> 4, l = tid & 15;
            const unsigned* wrow = woS + jj * 520 + l * 25;
            const float* crow = (l < 8) ? (h1f + l * 50) : (h2l + (l - 8) * 50);
            float s = 0.f;
            #pragma unroll
            for (int i2 = 0; i2 < 25; ++i2) {
                unsigned wv = wrow[i2];
                float clo = crow[2 * i2], chi = crow[2 * i2 + 1];
                FMIX_LO(s, wv, clo);
                FMIX_HI(s, wv, chi);
            }
            s += __shfl_down(s, 8, 16);
            s += __shfl_down(s, 4, 16);
            s += __shfl_down(s, 2, 16);
            s += __shfl_down(s, 1, 16);
            if (l == 0) ps[jj] = s + bo[jlo + jj];
        }
        __syncthreads();
        {
            const size_t nt_ = (size_t)b * NT + gt;
            if (tid < jcnt) {
                int j = jlo + tid;
                float v = ps[tid];
                if (j == 120) {
                    outp[OFF_END + nt_] = sigm(v);
                } else if (j < 20) {   // only r==0 block reaches here
                    float mx = -1e30f;
                    #pragma unroll
                    for (int m = 0; m < NM; ++m) mx = fmaxf(mx, ps[m]);
                    float sm = 0.f;
                    #pragma unroll
                    for (int m = 0; m < NM; ++m) sm += expf(ps[m] - mx);
                    outp[OFF_W + nt_ * NM + j] = expf(v - mx) / sm;
                } else {
                    int sec = j / 20, idx = j - sec * 20;
                    float o = (sec == 5) ? tanhf(v) : v;
                    unsigned offs = (sec == 1) ? OFF_MU1 : (sec == 2) ? OFF_MU2 :
                                    (sec == 3) ? OFF_LS1 : (sec == 4) ? OFF_LS2 : OFF_RHO;
                    outp[offs + nt_ * NM + idx] = o;
                }
            }
        }
        __syncthreads();
    }
    if (tid < 100) {
        int cbase = r * 100 + tid;
        h2st[b * CS + cbase] = h2l[cbase];
        c2st[b * CS + cbase] = c2l[tid];
        if (last) {
            outp[OFF_H2 + b * CS + cbase] = h2l[cbase];
            outp[OFF_C2 + b * CS + cbase] = c2l[tid];
        }
    }
}

// ---------------------------------------------------------------- launch
extern "C" void kernel_launch(void* const* d_in, const int* in_sizes, int n_in,
                              void* d_out, int out_size, void* d_ws, size_t ws_size,
                              hipStream_t stream) {
    const float* x    = (const float*)d_in[0];
    const float* oh   = (const float*)d_in[1];
    const float* tl   = (const float*)d_in[2];
    const float* w0   = (const float*)d_in[3];
    const float* kp0  = (const float*)d_in[4];
    const float* h10  = (const float*)d_in[5];
    const float* c10  = (const float*)d_in[6];
    const float* h20  = (const float*)d_in[7];
    const float* c20  = (const float*)d_in[8];
    const float* W1ih = (const float*)d_in[9];
    const float* W1hh = (const float*)d_in[10];
    const float* b1   = (const float*)d_in[11];
    const float* Ww   = (const float*)d_in[12];
    const float* bw   = (const float*)d_in[13];
    const float* W2ih = (const float*)d_in[14];
    const float* W2hh = (const float*)d_in[15];
    const float* b2   = (const float*)d_in[16];
    const float* Wo   = (const float*)d_in[17];
    const float* bo   = (const float*)d_in[18];
    float* outp = (float*)d_out;

    char* p = (char*)d_ws;
    auto alloc = [&](size_t bytes) { char* r = p; p += (bytes + 255) & ~(size_t)255; return r; };
    ush*   W1P  = (ush*)  alloc((size_t)K1PAD * G4 * 2);
    ush*   W2T  = (ush*)  alloc((size_t)863 * G4 * 2);
    ush*   WoB  = (ush*)  alloc((size_t)NP * CAT * 2);
    ush*   Apan = (ush*)  alloc((size_t)NT * NB * APK * 2);   // A panel (f16)
    float* h2st = (float*)alloc((size_t)NB * CS * 4);
    float* c2st = (float*)alloc((size_t)NB * CS * 4);
    float* hx1  = (float*)alloc((size_t)2 * NB * CS * 4);
    float* hx2  = (float*)alloc((size_t)2 * NB * CS * 4);
    float* hxp  = (float*)alloc((size_t)2 * NB * 128 * 4);    // attention partials
    unsigned* flg = (unsigned*)alloc(2 * NB * FLGS * 4);  // padded: 256B/batch/scan

    // Zb gets whatever remains: pick the largest chunk length that fits.
    size_t used = (size_t)(p - (char*)d_ws);
    size_t rem  = (ws_size > used + 256) ? (ws_size - used - 256) : 0;
    size_t per_t = (size_t)NB * G4 * 2;            // bytes of Z per timestep
    int tc = (int)(rem / per_t);
    if (tc < 76) tc = 76;                          // fallback chunking
    if (tc > NT) tc = NT;
    int nch = (NT + tc - 1) / tc;
    tc = (NT + nch - 1) / nch;                     // balance chunk sizes
    if (tc & 1) ++tc;                              // gemmZ needs even len (128-row tiles)
    ush* Zb = (ush*)alloc((size_t)tc * NB * G4 * 2);

    hipMemsetAsync(flg, 0, 2 * NB * FLGS * 4, stream);
    hipMemsetAsync(Apan, 0, (size_t)NT * NB * APK * 2, stream);  // zeroes the k-pad cols
    prep_k<<<(863 * G4 + 255) / 256, 256, 0, stream>>>(W1ih, W1hh, W2ih, W2hh, Wo,
                                                       W1P, W2T, WoB);
    scan1_k<<<4 * NB, 512, 0, stream>>>(x, oh, tl, w0, kp0, h10, c10, b1, Ww, bw, W1P,
                                        Apan, outp, hx1, hxp, flg);
    for (int c = 0; c < nch; ++c) {
        int t0 = c * tc;
        int len = (t0 + tc <= NT) ? tc : (NT - t0);
        gemmZ_k<<<dim3(G4 / 64, len * NB / 128), 256, 0, stream>>>(
            Apan, W2T, b2, Zb, t0 * NB);
        scan2_k<<<4 * NB, 512, 0, stream>>>(
            Zb, W2T, WoB, Apan, bo, h20, c20, h2st, c2st, outp, hx2, flg + NB * FLGS,
            t0, len, c == 0, c == nch - 1);
    }
}